// Round 1
// baseline (1241.484 us; speedup 1.0000x reference)
//
#include <hip/hip_runtime.h>
#include <hip/hip_bf16.h>
#include <hip/hip_fp16.h>
#include <math.h>

#define T_TOK 8192
#define DIM   1024
#define HID   4096
#define NE    8
#define NTILES 136                 // ceil(T*K/128) + E slack = 128 + 8
#define CAP_ROWS (NTILES * 128)    // 17408 padded slots

typedef _Float16 f16x8 __attribute__((ext_vector_type(8)));
typedef float    floatx4 __attribute__((ext_vector_type(4)));

__device__ __forceinline__ void gload_lds16(const void* g, void* l) {
    __builtin_amdgcn_global_load_lds(
        (const __attribute__((address_space(1))) void*)g,
        (__attribute__((address_space(3))) void*)l,
        16, 0, 0);
}

// ---------------- Pass 1a: gating + LN stats ----------------
__global__ __launch_bounds__(256) void gating_ln_kernel(
    const float* __restrict__ x, const float* __restrict__ gw,
    int* __restrict__ sel, float* __restrict__ wts,
    float* __restrict__ mu_arr, float* __restrict__ rstd_arr,
    int* __restrict__ counts)
{
    int t = blockIdx.x;
    int tid = threadIdx.x;
    float4 xv = ((const float4*)(x + (size_t)t * DIM))[tid];
    float s  = xv.x + xv.y + xv.z + xv.w;
    float ss = xv.x*xv.x + xv.y*xv.y + xv.z*xv.z + xv.w*xv.w;
    float l[NE];
#pragma unroll
    for (int e = 0; e < NE; e++) l[e] = 0.f;
    int d0 = tid * 4;
    const float* xp = &xv.x;
#pragma unroll
    for (int j = 0; j < 4; j++) {
        float xj = xp[j];
        const float4* g = (const float4*)(gw + (size_t)(d0 + j) * NE);
        float4 g0 = g[0], g1 = g[1];
        l[0] += xj * g0.x; l[1] += xj * g0.y; l[2] += xj * g0.z; l[3] += xj * g0.w;
        l[4] += xj * g1.x; l[5] += xj * g1.y; l[6] += xj * g1.z; l[7] += xj * g1.w;
    }
#pragma unroll
    for (int off = 32; off > 0; off >>= 1) {
        s  += __shfl_down(s, off);
        ss += __shfl_down(ss, off);
#pragma unroll
        for (int e = 0; e < NE; e++) l[e] += __shfl_down(l[e], off);
    }
    __shared__ float red[4][10];
    int lane = tid & 63, wv = tid >> 6;
    if (lane == 0) {
        red[wv][0] = s; red[wv][1] = ss;
        for (int e = 0; e < NE; e++) red[wv][2 + e] = l[e];
    }
    __syncthreads();
    if (tid == 0) {
        float S = 0.f, SS = 0.f, L[NE];
        for (int e = 0; e < NE; e++) L[e] = 0.f;
        for (int w = 0; w < 4; w++) {
            S += red[w][0]; SS += red[w][1];
            for (int e = 0; e < NE; e++) L[e] += red[w][2 + e];
        }
        float mu  = S * (1.f / DIM);
        float var = SS * (1.f / DIM) - mu * mu;
        float rstd = rsqrtf(var + 1e-5f);
        float lmax = L[0];
        for (int e = 1; e < NE; e++) lmax = fmaxf(lmax, L[e]);
        float den = 0.f;
        for (int e = 0; e < NE; e++) den += expf(L[e] - lmax);
        // top-2 with first-index tie semantics (matches jax.lax.top_k)
        int i0 = 0; float b0 = L[0];
        for (int e = 1; e < NE; e++) if (L[e] > b0) { b0 = L[e]; i0 = e; }
        int i1 = -1; float b1v = -3.4e38f;
        for (int e = 0; e < NE; e++) if (e != i0 && L[e] > b1v) { b1v = L[e]; i1 = e; }
        float p0 = expf(b0 - lmax) / den;
        float p1 = expf(b1v - lmax) / den;
        // reference: softmax over the top-k *probabilities*
        float t1 = expf(p1 - p0);            // p1 <= p0, so stable
        float w0 = 1.f / (1.f + t1);
        float w1 = t1 / (1.f + t1);
        sel[2*t] = i0;  sel[2*t+1] = i1;
        wts[2*t] = w0;  wts[2*t+1] = w1;
        mu_arr[t] = mu; rstd_arr[t] = rstd;
        atomicAdd(&counts[i0], 1);
        atomicAdd(&counts[i1], 1);
    }
}

// ---------------- Pass 1b: 128-aligned offsets + tile->expert map ----------------
__global__ void build_offsets_kernel(const int* __restrict__ counts, int* __restrict__ off,
                                     int* __restrict__ cursor, int* __restrict__ tile_expert)
{
    if (threadIdx.x != 0 || blockIdx.x != 0) return;
    int o = 0;
    for (int e = 0; e < NE; e++) {
        off[e] = o;
        o += ((counts[e] + 127) >> 7) << 7;
        cursor[e] = 0;
    }
    off[NE] = o;
    for (int tIdx = 0; tIdx < NTILES; tIdx++) {
        int pos = tIdx * 128;
        int e = -1;
        if (pos < o) {
            for (int j = 0; j < NE; j++)
                if (pos >= off[j] && pos < off[j+1]) { e = j; break; }
        }
        tile_expert[tIdx] = e;
    }
}

// ---------------- Pass 1c: scatter normalized tokens (LN affine folded) ----------------
__global__ __launch_bounds__(256) void scatter_kernel(
    const float* __restrict__ x, const float* __restrict__ ln_s, const float* __restrict__ ln_b,
    const int* __restrict__ sel, const float* __restrict__ wts,
    const float* __restrict__ mu_arr, const float* __restrict__ rstd_arr,
    const int* __restrict__ off, int* __restrict__ cursor,
    _Float16* __restrict__ xg, int* __restrict__ tok_of, float* __restrict__ wt_of)
{
    int t = blockIdx.x, tid = threadIdx.x;
    __shared__ int sslot[2];
    int e0 = sel[2*t], e1 = sel[2*t+1];
    if (tid == 0) {
        int s0 = off[e0] + atomicAdd(&cursor[e0], 1);
        int s1 = off[e1] + atomicAdd(&cursor[e1], 1);
        sslot[0] = s0; sslot[1] = s1;
        tok_of[s0] = t; tok_of[s1] = t;
        wt_of[s0] = wts[2*t]; wt_of[s1] = wts[2*t+1];
    }
    __syncthreads();
    float4 xv = ((const float4*)(x + (size_t)t * DIM))[tid];
    float mu = mu_arr[t], rstd = rstd_arr[t];
    float xn0 = (xv.x - mu) * rstd, xn1 = (xv.y - mu) * rstd;
    float xn2 = (xv.z - mu) * rstd, xn3 = (xv.w - mu) * rstd;
#pragma unroll
    for (int k = 0; k < 2; k++) {
        int e = (k == 0) ? e0 : e1;
        int slot = sslot[k];
        float4 sv = ((const float4*)(ln_s + (size_t)e * DIM))[tid];
        float4 bv = ((const float4*)(ln_b + (size_t)e * DIM))[tid];
        _Float16 hb[4];
        hb[0] = (_Float16)(xn0 * sv.x + bv.x);
        hb[1] = (_Float16)(xn1 * sv.y + bv.y);
        hb[2] = (_Float16)(xn2 * sv.z + bv.z);
        hb[3] = (_Float16)(xn3 * sv.w + bv.w);
        *(uint2*)(xg + (size_t)slot * DIM + tid * 4) = *(const uint2*)hb;
    }
}

// ---------------- Weight transpose + fp32->fp16 convert ----------------
// in: [batch][R][C] fp32 -> out: [batch][C][R] fp16
__global__ void transpose_cvt_kernel(const float* __restrict__ in, _Float16* __restrict__ out,
                                     int R, int C)
{
    __shared__ _Float16 tile[64][65];
    size_t ebase = (size_t)blockIdx.z * R * C;
    const float* inp = in + ebase;
    _Float16* outp = out + ebase;
    int c0 = blockIdx.x * 64, r0 = blockIdx.y * 64;
    int tx = threadIdx.x, ty = threadIdx.y;
    for (int j = ty; j < 64; j += 4)
        tile[j][tx] = (_Float16)inp[(size_t)(r0 + j) * C + c0 + tx];
    __syncthreads();
    for (int j = ty; j < 64; j += 4)
        outp[(size_t)(c0 + j) * R + r0 + tx] = tile[tx][j];
}

// ---------------- GEMM1: H1 = gelu(xg @ w1 + b1), fp16 in, fp16 out ----------------
__global__ __launch_bounds__(256) void gemm1_kernel(
    const _Float16* __restrict__ xg,   // [CAP][DIM]
    const _Float16* __restrict__ w1t,  // [E][HID][DIM]
    const float* __restrict__ b1,      // [E][HID]
    const int* __restrict__ tile_expert,
    _Float16* __restrict__ H1)         // [CAP][HID]
{
    __shared__ _Float16 As[128 * 32];
    __shared__ _Float16 Bs[128 * 32];
    int e = tile_expert[blockIdx.y];
    if (e < 0) return;
    int row0 = blockIdx.y * 128;
    int n0 = blockIdx.x * 128;
    const _Float16* Abase = xg + (size_t)row0 * DIM;
    const _Float16* Bbase = w1t + ((size_t)e * HID + n0) * DIM;
    int tid = threadIdx.x;
    int lane = tid & 63, wv = tid >> 6;
    int wm = wv >> 1, wn = wv & 1;
    int lm = lane & 15, kq = lane >> 4;
    floatx4 acc[4][4] = {};

    for (int k0 = 0; k0 < DIM; k0 += 32) {
#pragma unroll
        for (int r = 0; r < 2; r++) {
            int j = r * 256 + tid;
            int arow = j >> 2;
            int acol = (j & 3) * 8;
            gload_lds16(Abase + (size_t)arow * DIM + (k0 + acol), (char*)As + j * 16);
            gload_lds16(Bbase + (size_t)arow * DIM + (k0 + acol), (char*)Bs + j * 16);
        }
        __syncthreads();
        f16x8 af[4], bf[4];
#pragma unroll
        for (int tm = 0; tm < 4; tm++)
            af[tm] = *(const f16x8*)(As + (wm*64 + tm*16 + lm) * 32 + kq * 8);
#pragma unroll
        for (int tn = 0; tn < 4; tn++)
            bf[tn] = *(const f16x8*)(Bs + (wn*64 + tn*16 + lm) * 32 + kq * 8);
#pragma unroll
        for (int tm = 0; tm < 4; tm++)
#pragma unroll
            for (int tn = 0; tn < 4; tn++)
                acc[tm][tn] = __builtin_amdgcn_mfma_f32_16x16x32_f16(af[tm], bf[tn], acc[tm][tn], 0, 0, 0);
        __syncthreads();
    }
    const float* b1e = b1 + (size_t)e * HID + n0;
    float bias[4];
#pragma unroll
    for (int tn = 0; tn < 4; tn++) bias[tn] = b1e[wn*64 + tn*16 + lm];
#pragma unroll
    for (int tm = 0; tm < 4; tm++) {
        int rbase = row0 + wm*64 + tm*16 + kq*4;
#pragma unroll
        for (int tn = 0; tn < 4; tn++) {
            int h = n0 + wn*64 + tn*16 + lm;
#pragma unroll
            for (int r = 0; r < 4; r++) {
                float v = acc[tm][tn][r] + bias[tn];
                v = 0.5f * v * (1.f + erff(v * 0.70710678118654752f));  // exact gelu
                H1[(size_t)(rbase + r) * HID + h] = (_Float16)v;
            }
        }
    }
}

// ---------------- GEMM2: out[tok] += wt * (H1 @ w2 + b2) ----------------
__global__ __launch_bounds__(256) void gemm2_kernel(
    const _Float16* __restrict__ H1,   // [CAP][HID]
    const _Float16* __restrict__ w2t,  // [E][DIM][HID]
    const float* __restrict__ b2,      // [E][DIM]
    const int* __restrict__ tile_expert,
    const int* __restrict__ off, const int* __restrict__ counts,
    const int* __restrict__ tok_of, const float* __restrict__ wt_of,
    float* __restrict__ out)
{
    __shared__ _Float16 As[128 * 32];
    __shared__ _Float16 Bs[128 * 32];
    int e = tile_expert[blockIdx.y];
    if (e < 0) return;
    int row0 = blockIdx.y * 128;
    int n0 = blockIdx.x * 128;
    const _Float16* Abase = H1 + (size_t)row0 * HID;
    const _Float16* Bbase = w2t + ((size_t)e * DIM + n0) * HID;
    int tid = threadIdx.x;
    int lane = tid & 63, wv = tid >> 6;
    int wm = wv >> 1, wn = wv & 1;
    int lm = lane & 15, kq = lane >> 4;
    floatx4 acc[4][4] = {};

    for (int k0 = 0; k0 < HID; k0 += 32) {
#pragma unroll
        for (int r = 0; r < 2; r++) {
            int j = r * 256 + tid;
            int arow = j >> 2;
            int acol = (j & 3) * 8;
            gload_lds16(Abase + (size_t)arow * HID + (k0 + acol), (char*)As + j * 16);
            gload_lds16(Bbase + (size_t)arow * HID + (k0 + acol), (char*)Bs + j * 16);
        }
        __syncthreads();
        f16x8 af[4], bf[4];
#pragma unroll
        for (int tm = 0; tm < 4; tm++)
            af[tm] = *(const f16x8*)(As + (wm*64 + tm*16 + lm) * 32 + kq * 8);
#pragma unroll
        for (int tn = 0; tn < 4; tn++)
            bf[tn] = *(const f16x8*)(Bs + (wn*64 + tn*16 + lm) * 32 + kq * 8);
#pragma unroll
        for (int tm = 0; tm < 4; tm++)
#pragma unroll
            for (int tn = 0; tn < 4; tn++)
                acc[tm][tn] = __builtin_amdgcn_mfma_f32_16x16x32_f16(af[tm], bf[tn], acc[tm][tn], 0, 0, 0);
        __syncthreads();
    }
    int end = off[e] + counts[e];
    const float* b2e = b2 + (size_t)e * DIM + n0;
    float bias[4];
#pragma unroll
    for (int tn = 0; tn < 4; tn++) bias[tn] = b2e[wn*64 + tn*16 + lm];
#pragma unroll
    for (int tm = 0; tm < 4; tm++) {
        int rbase = row0 + wm*64 + tm*16 + kq*4;
#pragma unroll
        for (int r = 0; r < 4; r++) {
            int slot = rbase + r;
            if (slot >= end) continue;            // padded row -> skip
            int tok = tok_of[slot];
            float wt = wt_of[slot];
#pragma unroll
            for (int tn = 0; tn < 4; tn++) {
                int d = n0 + wn*64 + tn*16 + lm;
                float v = acc[tm][tn][r] + bias[tn];
                unsafeAtomicAdd(&out[(size_t)tok * DIM + d], wt * v);
            }
        }
    }
}

extern "C" void kernel_launch(void* const* d_in, const int* in_sizes, int n_in,
                              void* d_out, int out_size, void* d_ws, size_t ws_size,
                              hipStream_t stream)
{
    const float* x    = (const float*)d_in[0];
    const float* gw   = (const float*)d_in[1];
    const float* ln_s = (const float*)d_in[2];
    const float* ln_b = (const float*)d_in[3];
    const float* w1   = (const float*)d_in[4];
    const float* b1   = (const float*)d_in[5];
    const float* w2   = (const float*)d_in[6];
    const float* b2   = (const float*)d_in[7];
    float* out = (float*)d_out;

    char* p = (char*)d_ws;
    auto carve = [&](size_t bytes) -> char* {
        char* r = p;
        p += (bytes + 255) & ~(size_t)255;
        return r;
    };
    int*   counts   = (int*)carve(NE * 4);
    int*   cursor   = (int*)carve(NE * 4);
    int*   off      = (int*)carve((NE + 1) * 4);
    int*   tile_exp = (int*)carve(NTILES * 4);
    int*   sel      = (int*)carve((size_t)T_TOK * 2 * 4);
    float* wts      = (float*)carve((size_t)T_TOK * 2 * 4);
    float* mu_arr   = (float*)carve((size_t)T_TOK * 4);
    float* rstd_arr = (float*)carve((size_t)T_TOK * 4);
    int*   tok_of   = (int*)carve((size_t)CAP_ROWS * 4);
    float* wt_of    = (float*)carve((size_t)CAP_ROWS * 4);
    _Float16* xg  = (_Float16*)carve((size_t)CAP_ROWS * DIM * 2);
    _Float16* w1t = (_Float16*)carve((size_t)NE * DIM * HID * 2);
    _Float16* w2t = (_Float16*)carve((size_t)NE * DIM * HID * 2);
    _Float16* H1  = (_Float16*)carve((size_t)CAP_ROWS * HID * 2);

    hipMemsetAsync(counts, 0, NE * 4, stream);
    hipMemsetAsync(d_out, 0, (size_t)out_size * 4, stream);

    gating_ln_kernel<<<T_TOK, 256, 0, stream>>>(x, gw, sel, wts, mu_arr, rstd_arr, counts);
    build_offsets_kernel<<<1, 1, 0, stream>>>(counts, off, cursor, tile_exp);
    scatter_kernel<<<T_TOK, 256, 0, stream>>>(x, ln_s, ln_b, sel, wts, mu_arr, rstd_arr,
                                              off, cursor, xg, tok_of, wt_of);
    // w1: [E][D][H] -> [E][H][D]
    transpose_cvt_kernel<<<dim3(HID/64, DIM/64, NE), dim3(64, 4), 0, stream>>>(w1, w1t, DIM, HID);
    // w2: [E][H][D] -> [E][D][H]
    transpose_cvt_kernel<<<dim3(DIM/64, HID/64, NE), dim3(64, 4), 0, stream>>>(w2, w2t, HID, DIM);

    gemm1_kernel<<<dim3(HID/128, NTILES), 256, 0, stream>>>(xg, w1t, b1, tile_exp, H1);
    gemm2_kernel<<<dim3(DIM/128, NTILES), 256, 0, stream>>>(H1, w2t, b2, tile_exp, off, counts,
                                                            tok_of, wt_of, out);
}